// Round 5
// baseline (474.643 us; speedup 1.0000x reference)
//
#include <hip/hip_runtime.h>
#include <hip/hip_fp16.h>
#include <cmath>

#define T_TOKENS 8192
#define HID 2048
#define NEXP 8
#define INTERM 1024
#define GATE_NB 2048

typedef _Float16 f16x8 __attribute__((ext_vector_type(8)));
typedef _Float16 f16x4 __attribute__((ext_vector_type(4)));
typedef float f32x4 __attribute__((ext_vector_type(4)));

static __device__ __forceinline__ float gelu_tanh(float v) {
    return 0.5f * v * (1.0f + tanhf(0.79788456080286535588f * (v + 0.044715f * v * v * v)));
}

static __device__ __forceinline__ void glds16(const void* g, void* l) {
    __builtin_amdgcn_global_load_lds((const __attribute__((address_space(1))) void*)g,
                                     (__attribute__((address_space(3))) void*)l, 16, 0, 0);
}

// swizzled LDS read: tile stored [256][64] fp16 (128B rows), phys chunk = chunk ^ (row&7)
static __device__ __forceinline__ f16x8 lds_read(const _Float16* base, int row, int chunk) {
    int phys = chunk ^ (row & 7);
    return *reinterpret_cast<const f16x8*>(
        reinterpret_cast<const char*>(base) + row * 128 + phys * 16);
}

// ------------- fp32 [Z][R][C] -> fp16 [Z][C][R] transpose-convert -------------
__global__ __launch_bounds__(256) void tconv_kernel(const float* __restrict__ in,
                                                    _Float16* __restrict__ out,
                                                    int R, int C) {
    __shared__ float t[32][33];
    int z = blockIdx.z;
    int r0 = blockIdx.y * 32, c0 = blockIdx.x * 32;
    int tid = threadIdx.x;
    int r = tid >> 3, c4 = (tid & 7) * 4;
    const float4 v = *reinterpret_cast<const float4*>(&in[((size_t)z * R + (r0 + r)) * C + c0 + c4]);
    t[r][c4 + 0] = v.x; t[r][c4 + 1] = v.y; t[r][c4 + 2] = v.z; t[r][c4 + 3] = v.w;
    __syncthreads();
    int oc = tid >> 3;
    int or4 = (tid & 7) * 4;
    f16x4 o;
    o[0] = (_Float16)t[or4 + 0][oc];
    o[1] = (_Float16)t[or4 + 1][oc];
    o[2] = (_Float16)t[or4 + 2][oc];
    o[3] = (_Float16)t[or4 + 3][oc];
    *reinterpret_cast<f16x4*>(&out[((size_t)z * C + (c0 + oc)) * R + r0 + or4]) = o;
}

// -------- gating: one wave per token; also emits xh = fp16(x) on the fly --------
__global__ __launch_bounds__(256) void gate_kernel(const float* __restrict__ x,
                                                   const float* __restrict__ gw,
                                                   _Float16* __restrict__ xh,
                                                   int* __restrict__ tk_idx, float* __restrict__ tk_w,
                                                   int* __restrict__ part_cnt,
                                                   double* __restrict__ part_sumP) {
    __shared__ double sds[4][NEXP];
    __shared__ int sci[4][NEXP];
    int w = threadIdx.x >> 6;
    int lane = threadIdx.x & 63;
    int t = blockIdx.x * 4 + w;

    const float4* xr = (const float4*)(x + (size_t)t * HID);
    _Float16* xo = xh + (size_t)t * HID;
    double acc[NEXP];
#pragma unroll
    for (int e = 0; e < NEXP; e++) acc[e] = 0.0;
#pragma unroll
    for (int i = 0; i < HID / 256; i++) {
        float4 xv = xr[i * 64 + lane];
        f16x4 h;
        h[0] = (_Float16)xv.x; h[1] = (_Float16)xv.y;
        h[2] = (_Float16)xv.z; h[3] = (_Float16)xv.w;
        *reinterpret_cast<f16x4*>(xo + i * 256 + lane * 4) = h;
#pragma unroll
        for (int e = 0; e < NEXP; e++) {
            float4 gv = ((const float4*)(gw + (size_t)e * HID))[i * 64 + lane];
            acc[e] += (double)xv.x * (double)gv.x + (double)xv.y * (double)gv.y
                    + (double)xv.z * (double)gv.z + (double)xv.w * (double)gv.w;
        }
    }
#pragma unroll
    for (int e = 0; e < NEXP; e++) {
#pragma unroll
        for (int off = 32; off > 0; off >>= 1) acc[e] += __shfl_xor(acc[e], off, 64);
    }
    double mx = acc[0];
#pragma unroll
    for (int e = 1; e < NEXP; e++) mx = acc[e] > mx ? acc[e] : mx;
    double ex[NEXP];
    double sum = 0.0;
#pragma unroll
    for (int e = 0; e < NEXP; e++) { ex[e] = exp(acc[e] - mx); sum += ex[e]; }
    int i0 = 0;
#pragma unroll
    for (int e = 1; e < NEXP; e++) if (ex[e] > ex[i0]) i0 = e;
    int i1 = (i0 == 0) ? 1 : 0;
#pragma unroll
    for (int e = 0; e < NEXP; e++) if (e != i0 && ex[e] > ex[i1]) i1 = e;
    double p0 = ex[i0], p1 = ex[i1];
    double t2 = p0 + p1;
    if (lane == 0) {
        tk_idx[2 * t] = i0; tk_idx[2 * t + 1] = i1;
        tk_w[2 * t] = (float)(p0 / t2); tk_w[2 * t + 1] = (float)(p1 / t2);
#pragma unroll
        for (int e = 0; e < NEXP; e++) {
            sds[w][e] = ex[e] / sum;
            sci[w][e] = (e == i0 ? 1 : 0) + (e == i1 ? 1 : 0);
        }
    }
    __syncthreads();
    if (threadIdx.x < NEXP) {
        int e = threadIdx.x;
        part_sumP[e * GATE_NB + blockIdx.x] = sds[0][e] + sds[1][e] + sds[2][e] + sds[3][e];
        part_cnt[e * GATE_NB + blockIdx.x]  = sci[0][e] + sci[1][e] + sci[2][e] + sci[3][e];
    }
}

// ---------------- reduce partials, offsets scan, aux loss, zero cursor ----------------
__global__ __launch_bounds__(256) void finalize_kernel(const int* __restrict__ part_cnt,
                                                       const double* __restrict__ part_sumP,
                                                       int* __restrict__ cnt, int* __restrict__ offs,
                                                       int* __restrict__ cursor,
                                                       float* __restrict__ aux_out) {
    __shared__ double swv[4];
    __shared__ int cwv[4];
    __shared__ double sE[NEXP];
    __shared__ int cE[NEXP];
    int w = threadIdx.x >> 6;
    int lane = threadIdx.x & 63;
    for (int e = 0; e < NEXP; e++) {
        double s = 0.0; int c = 0;
        for (int j = threadIdx.x; j < GATE_NB; j += 256) {
            s += part_sumP[e * GATE_NB + j];
            c += part_cnt[e * GATE_NB + j];
        }
#pragma unroll
        for (int off = 32; off > 0; off >>= 1) {
            s += __shfl_xor(s, off, 64);
            c += __shfl_xor(c, off, 64);
        }
        if (lane == 0) { swv[w] = s; cwv[w] = c; }
        __syncthreads();
        if (threadIdx.x == 0) {
            sE[e] = swv[0] + swv[1] + swv[2] + swv[3];
            cE[e] = cwv[0] + cwv[1] + cwv[2] + cwv[3];
        }
        __syncthreads();
    }
    if (threadIdx.x == 0) {
        int off = 0;
        double aux = 0.0;
#pragma unroll
        for (int e = 0; e < NEXP; e++) {
            cnt[e] = cE[e];
            offs[e] = off;
            off += cE[e];
            cursor[e] = 0;
            aux += ((double)cE[e] / (double)T_TOKENS) * (sE[e] / (double)T_TOKENS);
        }
        aux_out[0] = (float)(0.01 * (double)NEXP * aux);
    }
}

// ------- build per-expert row lists + inverse map (wave-aggregated atomics) -------
__global__ void scatter_kernel(const int* __restrict__ tk_idx, const float* __restrict__ tk_w,
                               const int* __restrict__ offs, int* __restrict__ cursor,
                               int* __restrict__ row_tok, float* __restrict__ row_w,
                               int* __restrict__ tok_row) {
    int t = blockIdx.x * blockDim.x + threadIdx.x;
    int lane = threadIdx.x & 63;
    unsigned long long below = (lane == 0) ? 0ull : ((~0ull) >> (64 - lane));
    for (int k = 0; k < 2; k++) {
        int e = tk_idx[2 * t + k];
        float wv = tk_w[2 * t + k];
        int pos = 0;
#pragma unroll
        for (int ee = 0; ee < NEXP; ee++) {
            unsigned long long m = __ballot(e == ee);
            if (e == ee) {
                int rank = (int)__popcll(m & below);
                int leader = (int)__ffsll((unsigned long long)m) - 1;
                int b = 0;
                if (lane == leader) b = atomicAdd(&cursor[ee], (int)__popcll(m));
                b = __shfl(b, leader, 64);
                pos = b + rank;
            }
        }
        int r = offs[e] + pos;
        row_tok[r] = t;
        row_w[r] = wv;
        tok_row[2 * t + k] = r;
    }
}

// ============ 256x256 tile, BK=64, 8-wave, 8-phase grouped GEMM ============
// Per wave: 128x64 output = 8x4 frags. 4 phases per K-tile (quadrant mh,nh),
// each phase: 12 ds_read_b128 + (0-2 glds) + barrier + lgkmcnt(0) + 16 MFMA + barrier.
// Counted vmcnt(4) once per K-tile; drains to 0 only at the last tile.
#define DO_PHASE(MH, NH, EXTRA) do {                                                   \
    f16x8 a_[4][2], b_[2][2];                                                          \
    _Pragma("unroll") for (int i_ = 0; i_ < 4; i_++)                                   \
    _Pragma("unroll") for (int k_ = 0; k_ < 2; k_++)                                   \
        a_[i_][k_] = lds_read(Ab, wr * 128 + ((MH) * 4 + i_) * 16 + fr, k_ * 4 + fq);  \
    _Pragma("unroll") for (int j_ = 0; j_ < 2; j_++)                                   \
    _Pragma("unroll") for (int k_ = 0; k_ < 2; k_++)                                   \
        b_[j_][k_] = lds_read(Bb, wc * 64 + ((NH) * 2 + j_) * 16 + fr, k_ * 4 + fq);   \
    EXTRA                                                                              \
    __builtin_amdgcn_s_barrier();                                                      \
    asm volatile("s_waitcnt lgkmcnt(0)" ::: "memory");                                 \
    __builtin_amdgcn_s_setprio(1);                                                     \
    _Pragma("unroll") for (int i_ = 0; i_ < 4; i_++)                                   \
    _Pragma("unroll") for (int j_ = 0; j_ < 2; j_++)                                   \
    _Pragma("unroll") for (int k_ = 0; k_ < 2; k_++)                                   \
        acc[(MH) * 4 + i_][(NH) * 2 + j_] = __builtin_amdgcn_mfma_f32_16x16x32_f16(    \
            a_[i_][k_], b_[j_][k_], acc[(MH) * 4 + i_][(NH) * 2 + j_], 0, 0, 0);       \
    __builtin_amdgcn_s_setprio(0);                                                     \
    __builtin_amdgcn_s_barrier();                                                      \
} while (0)

template<bool GATHER, bool GELU, int KTOT>
__global__ __launch_bounds__(512, 2) void gemm8_kernel(
    const _Float16* __restrict__ Aglob,
    const _Float16* __restrict__ Bglob,
    const int* __restrict__ cnt, const int* __restrict__ offs,
    const int* __restrict__ row_tok,
    _Float16* __restrict__ Out, int Ncols)
{
    constexpr int NT = KTOT / 64;
    int e = blockIdx.z;
    int Ne = cnt[e];
    int m0 = blockIdx.y * 256;
    if (m0 >= Ne) return;
    int base = offs[e];
    int n0 = blockIdx.x * 256;

    __shared__ __align__(16) _Float16 As[2][256][64];
    __shared__ __align__(16) _Float16 Bs[2][256][64];

    int tid = threadIdx.x;
    int w = tid >> 6;
    int lane = tid & 63;
    int wr = w >> 2, wc = w & 3;
    int fr = lane & 15, fq = lane >> 4;

    // ---- staging sources (pre-swizzled global chunk; LDS dest stays linear) ----
    int trow = tid >> 3;                    // 0..63: row-in-64-group
    int lc = (tid & 7) ^ (trow & 7);        // logical 16B chunk for this lane
    int ar0 = m0 + 0 * 64 + trow; if (ar0 >= Ne) ar0 = Ne - 1;
    int ar1 = m0 + 1 * 64 + trow; if (ar1 >= Ne) ar1 = Ne - 1;
    int ar2 = m0 + 2 * 64 + trow; if (ar2 >= Ne) ar2 = Ne - 1;
    int ar3 = m0 + 3 * 64 + trow; if (ar3 >= Ne) ar3 = Ne - 1;
    int id0 = GATHER ? row_tok[base + ar0] : (base + ar0);
    int id1 = GATHER ? row_tok[base + ar1] : (base + ar1);
    int id2 = GATHER ? row_tok[base + ar2] : (base + ar2);
    int id3 = GATHER ? row_tok[base + ar3] : (base + ar3);
    const _Float16* aSrc0 = Aglob + (size_t)id0 * KTOT + lc * 8;
    const _Float16* aSrc1 = Aglob + (size_t)id1 * KTOT + lc * 8;
    const _Float16* aSrc2 = Aglob + (size_t)id2 * KTOT + lc * 8;
    const _Float16* aSrc3 = Aglob + (size_t)id3 * KTOT + lc * 8;
    const size_t bexp = (size_t)e * Ncols * KTOT;
    const _Float16* bSrc0 = Bglob + bexp + (size_t)(n0 + 0 * 64 + trow) * KTOT + lc * 8;
    const _Float16* bSrc1 = Bglob + bexp + (size_t)(n0 + 1 * 64 + trow) * KTOT + lc * 8;
    const _Float16* bSrc2 = Bglob + bexp + (size_t)(n0 + 2 * 64 + trow) * KTOT + lc * 8;
    const _Float16* bSrc3 = Bglob + bexp + (size_t)(n0 + 3 * 64 + trow) * KTOT + lc * 8;

    _Float16* AsB = &As[0][0][0];
    _Float16* BsB = &Bs[0][0][0];
    _Float16* ldsA = AsB + w * 512;     // + q*4096 + slot*16384
    _Float16* ldsB = BsB + w * 512;

    f32x4 acc[8][4] = {};

    // prologue: stage tile 0 into slot 0 (8 issues)
    glds16(aSrc0, ldsA + 0 * 4096);
    glds16(aSrc1, ldsA + 1 * 4096);
    glds16(aSrc2, ldsA + 2 * 4096);
    glds16(aSrc3, ldsA + 3 * 4096);
    glds16(bSrc0, ldsB + 0 * 4096);
    glds16(bSrc1, ldsB + 1 * 4096);
    glds16(bSrc2, ldsB + 2 * 4096);
    glds16(bSrc3, ldsB + 3 * 4096);

    for (int j = 0; j < NT; ++j) {
        int slot = j & 1;
        const _Float16* Ab = AsB + slot * 16384;
        const _Float16* Bb = BsB + slot * 16384;
        _Float16* An = ldsA + (slot ^ 1) * 16384;
        _Float16* Bn = ldsB + (slot ^ 1) * 16384;
        int koff = (j + 1) * 64;
        bool more = (j + 1 < NT);
        if (more) {
            glds16(aSrc0 + koff, An + 0 * 4096);
            glds16(aSrc1 + koff, An + 1 * 4096);
            glds16(aSrc2 + koff, An + 2 * 4096);
            glds16(aSrc3 + koff, An + 3 * 4096);
            asm volatile("s_waitcnt vmcnt(4)" ::: "memory");
        } else {
            asm volatile("s_waitcnt vmcnt(0)" ::: "memory");
        }
        __builtin_amdgcn_s_barrier();
        DO_PHASE(0, 0, if (more) { glds16(bSrc0 + koff, Bn + 0 * 4096); glds16(bSrc1 + koff, Bn + 1 * 4096); });
        DO_PHASE(0, 1, if (more) { glds16(bSrc2 + koff, Bn + 2 * 4096); glds16(bSrc3 + koff, Bn + 3 * 4096); });
        DO_PHASE(1, 0, );
        DO_PHASE(1, 1, );
    }

    // ---- epilogue ----
#pragma unroll
    for (int mi = 0; mi < 8; mi++) {
#pragma unroll
        for (int r = 0; r < 4; r++) {
            int row = m0 + wr * 128 + mi * 16 + fq * 4 + r;
            if (row < Ne) {
                _Float16* dst = Out + (size_t)(base + row) * Ncols + n0 + wc * 64 + fr;
#pragma unroll
                for (int ni = 0; ni < 4; ni++) {
                    float v = acc[mi][ni][r];
                    if (GELU) v = gelu_tanh(v);
                    dst[ni * 16] = (_Float16)v;
                }
            }
        }
    }
}

// ---------------- combine: out[t] = w0*y[r0] + w1*y[r1] ----------------
__global__ __launch_bounds__(256) void combine_kernel(const _Float16* __restrict__ y,
                                                      const int* __restrict__ tok_row,
                                                      const float* __restrict__ tk_w,
                                                      float* __restrict__ out) {
    int t = blockIdx.x;
    int c = threadIdx.x;
    int r0 = tok_row[2 * t], r1 = tok_row[2 * t + 1];
    float w0 = tk_w[2 * t], w1 = tk_w[2 * t + 1];
    f16x8 a = reinterpret_cast<const f16x8*>(y + (size_t)r0 * HID)[c];
    f16x8 b = reinterpret_cast<const f16x8*>(y + (size_t)r1 * HID)[c];
    float4 o0, o1;
    o0.x = w0 * (float)a[0] + w1 * (float)b[0];
    o0.y = w0 * (float)a[1] + w1 * (float)b[1];
    o0.z = w0 * (float)a[2] + w1 * (float)b[2];
    o0.w = w0 * (float)a[3] + w1 * (float)b[3];
    o1.x = w0 * (float)a[4] + w1 * (float)b[4];
    o1.y = w0 * (float)a[5] + w1 * (float)b[5];
    o1.z = w0 * (float)a[6] + w1 * (float)b[6];
    o1.w = w0 * (float)a[7] + w1 * (float)b[7];
    float4* dst = reinterpret_cast<float4*>(out + (size_t)t * HID + c * 8);
    dst[0] = o0;
    dst[1] = o1;
}

extern "C" void kernel_launch(void* const* d_in, const int* in_sizes, int n_in,
                              void* d_out, int out_size, void* d_ws, size_t ws_size,
                              hipStream_t stream) {
    const float* x  = (const float*)d_in[0];
    const float* gw = (const float*)d_in[1];
    const float* w1 = (const float*)d_in[2];
    const float* w2 = (const float*)d_in[3];
    float* out = (float*)d_out;
    char* ws = (char*)d_ws;

    int*    cnt       = (int*)(ws + 0);
    int*    cursor    = (int*)(ws + 64);
    int*    offs      = (int*)(ws + 128);
    int*    part_cnt  = (int*)(ws + 4096);           // 8*2048*4 = 64KB
    double* part_sumP = (double*)(ws + 131072);      // 8*2048*8 = 128KB
    int*    row_tok   = (int*)(ws + 262144);         // 64KB
    float*  row_w     = (float*)(ws + 327680);       // 64KB
    int*    tk_idx    = (int*)(ws + 393216);         // 64KB
    float*  tk_w      = (float*)(ws + 458752);       // 64KB
    int*    tok_row   = (int*)(ws + 524288);         // 64KB
    const size_t OFF = 589824;
    _Float16* xh  = (_Float16*)(ws + OFF);                      // 32MB
    _Float16* w1t = (_Float16*)(ws + OFF + (1ull << 25));       // 32MB
    _Float16* w2t = (_Float16*)(ws + OFF + (2ull << 25));       // 32MB
    _Float16* hh  = (_Float16*)(ws + OFF + (3ull << 25));       // 32MB
    _Float16* y   = (_Float16*)(ws + OFF);   // 64MB, aliases xh+w1t (dead after gemm1)

    dim3 g1(INTERM / 32, HID / 32, NEXP);
    tconv_kernel<<<g1, 256, 0, stream>>>(w1, w1t, HID, INTERM);   // w1t[e][i][h]
    dim3 g2(HID / 32, INTERM / 32, NEXP);
    tconv_kernel<<<g2, 256, 0, stream>>>(w2, w2t, INTERM, HID);   // w2t[e][h][i]

    gate_kernel<<<GATE_NB, 256, 0, stream>>>(x, gw, xh, tk_idx, tk_w, part_cnt, part_sumP);
    finalize_kernel<<<1, 256, 0, stream>>>(part_cnt, part_sumP, cnt, offs, cursor,
                                           out + (size_t)T_TOKENS * HID);
    scatter_kernel<<<T_TOKENS / 256, 256, 0, stream>>>(tk_idx, tk_w, offs, cursor,
                                                       row_tok, row_w, tok_row);

    dim3 gg1(INTERM / 256, 32, NEXP);   // worst-case Ne=8192 -> 32 m-tiles
    gemm8_kernel<true, true, HID><<<gg1, 512, 0, stream>>>(xh, w1t, cnt, offs, row_tok, hh, INTERM);
    dim3 gg2(HID / 256, 32, NEXP);
    gemm8_kernel<false, false, INTERM><<<gg2, 512, 0, stream>>>(hh, w2t, cnt, offs, row_tok, y, HID);

    combine_kernel<<<T_TOKENS, 256, 0, stream>>>(y, tok_row, tk_w, out);
}

// Round 6
// 434.307 us; speedup vs baseline: 1.0929x; 1.0929x over previous
//
#include <hip/hip_runtime.h>
#include <hip/hip_fp16.h>
#include <cmath>

#define T_TOKENS 8192
#define HID 2048
#define NEXP 8
#define INTERM 1024
#define GATE_NB 2048
#define MAX_TT 72

typedef _Float16 f16x8 __attribute__((ext_vector_type(8)));
typedef _Float16 f16x4 __attribute__((ext_vector_type(4)));
typedef float f32x4 __attribute__((ext_vector_type(4)));

static __device__ __forceinline__ float gelu_tanh(float v) {
    return 0.5f * v * (1.0f + tanhf(0.79788456080286535588f * (v + 0.044715f * v * v * v)));
}

static __device__ __forceinline__ void glds16(const void* g, void* l) {
    __builtin_amdgcn_global_load_lds((const __attribute__((address_space(1))) void*)g,
                                     (__attribute__((address_space(3))) void*)l, 16, 0, 0);
}

// swizzled LDS read: tile stored [256][64] fp16 (128B rows), phys chunk = chunk ^ (row&7)
static __device__ __forceinline__ f16x8 lds_read(const _Float16* base, int row, int chunk) {
    int phys = chunk ^ (row & 7);
    return *reinterpret_cast<const f16x8*>(
        reinterpret_cast<const char*>(base) + row * 128 + phys * 16);
}

// ------------- fp32 [Z][R][C] -> fp16 [Z][C][R] transpose-convert -------------
__global__ __launch_bounds__(256) void tconv_kernel(const float* __restrict__ in,
                                                    _Float16* __restrict__ out,
                                                    int R, int C) {
    __shared__ float t[32][33];
    int z = blockIdx.z;
    int r0 = blockIdx.y * 32, c0 = blockIdx.x * 32;
    int tid = threadIdx.x;
    int r = tid >> 3, c4 = (tid & 7) * 4;
    const float4 v = *reinterpret_cast<const float4*>(&in[((size_t)z * R + (r0 + r)) * C + c0 + c4]);
    t[r][c4 + 0] = v.x; t[r][c4 + 1] = v.y; t[r][c4 + 2] = v.z; t[r][c4 + 3] = v.w;
    __syncthreads();
    int oc = tid >> 3;
    int or4 = (tid & 7) * 4;
    f16x4 o;
    o[0] = (_Float16)t[or4 + 0][oc];
    o[1] = (_Float16)t[or4 + 1][oc];
    o[2] = (_Float16)t[or4 + 2][oc];
    o[3] = (_Float16)t[or4 + 3][oc];
    *reinterpret_cast<f16x4*>(&out[((size_t)z * C + (c0 + oc)) * R + r0 + or4]) = o;
}

// -------- gating: one wave per token; also emits xh = fp16(x) on the fly --------
__global__ __launch_bounds__(256) void gate_kernel(const float* __restrict__ x,
                                                   const float* __restrict__ gw,
                                                   _Float16* __restrict__ xh,
                                                   int* __restrict__ tk_idx, float* __restrict__ tk_w,
                                                   int* __restrict__ part_cnt,
                                                   double* __restrict__ part_sumP) {
    __shared__ double sds[4][NEXP];
    __shared__ int sci[4][NEXP];
    int w = threadIdx.x >> 6;
    int lane = threadIdx.x & 63;
    int t = blockIdx.x * 4 + w;

    const float4* xr = (const float4*)(x + (size_t)t * HID);
    _Float16* xo = xh + (size_t)t * HID;
    double acc[NEXP];
#pragma unroll
    for (int e = 0; e < NEXP; e++) acc[e] = 0.0;
#pragma unroll
    for (int i = 0; i < HID / 256; i++) {
        float4 xv = xr[i * 64 + lane];
        f16x4 h;
        h[0] = (_Float16)xv.x; h[1] = (_Float16)xv.y;
        h[2] = (_Float16)xv.z; h[3] = (_Float16)xv.w;
        *reinterpret_cast<f16x4*>(xo + i * 256 + lane * 4) = h;
#pragma unroll
        for (int e = 0; e < NEXP; e++) {
            float4 gv = ((const float4*)(gw + (size_t)e * HID))[i * 64 + lane];
            acc[e] += (double)xv.x * (double)gv.x + (double)xv.y * (double)gv.y
                    + (double)xv.z * (double)gv.z + (double)xv.w * (double)gv.w;
        }
    }
#pragma unroll
    for (int e = 0; e < NEXP; e++) {
#pragma unroll
        for (int off = 32; off > 0; off >>= 1) acc[e] += __shfl_xor(acc[e], off, 64);
    }
    double mx = acc[0];
#pragma unroll
    for (int e = 1; e < NEXP; e++) mx = acc[e] > mx ? acc[e] : mx;
    double ex[NEXP];
    double sum = 0.0;
#pragma unroll
    for (int e = 0; e < NEXP; e++) { ex[e] = exp(acc[e] - mx); sum += ex[e]; }
    int i0 = 0;
#pragma unroll
    for (int e = 1; e < NEXP; e++) if (ex[e] > ex[i0]) i0 = e;
    int i1 = (i0 == 0) ? 1 : 0;
#pragma unroll
    for (int e = 0; e < NEXP; e++) if (e != i0 && ex[e] > ex[i1]) i1 = e;
    double p0 = ex[i0], p1 = ex[i1];
    double t2 = p0 + p1;
    if (lane == 0) {
        tk_idx[2 * t] = i0; tk_idx[2 * t + 1] = i1;
        tk_w[2 * t] = (float)(p0 / t2); tk_w[2 * t + 1] = (float)(p1 / t2);
#pragma unroll
        for (int e = 0; e < NEXP; e++) {
            sds[w][e] = ex[e] / sum;
            sci[w][e] = (e == i0 ? 1 : 0) + (e == i1 ? 1 : 0);
        }
    }
    __syncthreads();
    if (threadIdx.x < NEXP) {
        int e = threadIdx.x;
        part_sumP[e * GATE_NB + blockIdx.x] = sds[0][e] + sds[1][e] + sds[2][e] + sds[3][e];
        part_cnt[e * GATE_NB + blockIdx.x]  = sci[0][e] + sci[1][e] + sci[2][e] + sci[3][e];
    }
}

// ------- reduce partials, offsets scan, aux loss, zero cursor, tile table -------
__global__ __launch_bounds__(256) void finalize_kernel(const int* __restrict__ part_cnt,
                                                       const double* __restrict__ part_sumP,
                                                       int* __restrict__ cnt, int* __restrict__ offs,
                                                       int* __restrict__ cursor,
                                                       int* __restrict__ ttab,
                                                       float* __restrict__ aux_out) {
    __shared__ double swv[4];
    __shared__ int cwv[4];
    __shared__ double sE[NEXP];
    __shared__ int cE[NEXP];
    int w = threadIdx.x >> 6;
    int lane = threadIdx.x & 63;
    for (int e = 0; e < NEXP; e++) {
        double s = 0.0; int c = 0;
        for (int j = threadIdx.x; j < GATE_NB; j += 256) {
            s += part_sumP[e * GATE_NB + j];
            c += part_cnt[e * GATE_NB + j];
        }
#pragma unroll
        for (int off = 32; off > 0; off >>= 1) {
            s += __shfl_xor(s, off, 64);
            c += __shfl_xor(c, off, 64);
        }
        if (lane == 0) { swv[w] = s; cwv[w] = c; }
        __syncthreads();
        if (threadIdx.x == 0) {
            sE[e] = swv[0] + swv[1] + swv[2] + swv[3];
            cE[e] = cwv[0] + cwv[1] + cwv[2] + cwv[3];
        }
        __syncthreads();
    }
    if (threadIdx.x == 0) {
        int off = 0;
        double aux = 0.0;
        int idx = 0;
#pragma unroll
        for (int e = 0; e < NEXP; e++) {
            cnt[e] = cE[e];
            offs[e] = off;
            off += cE[e];
            cursor[e] = 0;
            aux += ((double)cE[e] / (double)T_TOKENS) * (sE[e] / (double)T_TOKENS);
            int mt = (cE[e] + 255) >> 8;
            for (int m = 0; m < mt; m++) ttab[idx++] = (e << 16) | m;
        }
        for (; idx < MAX_TT; idx++) ttab[idx] = -1;
        aux_out[0] = (float)(0.01 * (double)NEXP * aux);
    }
}

// ------- build per-expert row lists + inverse map (wave-aggregated atomics) -------
__global__ void scatter_kernel(const int* __restrict__ tk_idx, const float* __restrict__ tk_w,
                               const int* __restrict__ offs, int* __restrict__ cursor,
                               int* __restrict__ row_tok, float* __restrict__ row_w,
                               int* __restrict__ tok_row) {
    int t = blockIdx.x * blockDim.x + threadIdx.x;
    int lane = threadIdx.x & 63;
    unsigned long long below = (lane == 0) ? 0ull : ((~0ull) >> (64 - lane));
    for (int k = 0; k < 2; k++) {
        int e = tk_idx[2 * t + k];
        float wv = tk_w[2 * t + k];
        int pos = 0;
#pragma unroll
        for (int ee = 0; ee < NEXP; ee++) {
            unsigned long long m = __ballot(e == ee);
            if (e == ee) {
                int rank = (int)__popcll(m & below);
                int leader = (int)__ffsll((unsigned long long)m) - 1;
                int b = 0;
                if (lane == leader) b = atomicAdd(&cursor[ee], (int)__popcll(m));
                b = __shfl(b, leader, 64);
                pos = b + rank;
            }
        }
        int r = offs[e] + pos;
        row_tok[r] = t;
        row_w[r] = wv;
        tok_row[2 * t + k] = r;
    }
}

// ============ 256x256 tile, BK=64, 8-wave, 2-phase grouped GEMM ============
// Tile table (blockIdx.y) gives (expert, m-tile) -> contiguous active block ids.
// Per K-tile: phase0 {ds_read A-half0 (8) + B-all (8), 2 glds, bar, lgkm, 32 MFMA, bar}
//             phase1 {ds_read A-half1 (8), 2 glds, bar, lgkm, 32 MFMA, bar}
// B-frags persist in regs across both phases. Counted vmcnt(4) once per K-tile.
template<bool GATHER, bool GELU, int KTOT>
__global__ __launch_bounds__(512, 2) void gemm8_kernel(
    const _Float16* __restrict__ Aglob,
    const _Float16* __restrict__ Bglob,
    const int* __restrict__ cnt, const int* __restrict__ offs,
    const int* __restrict__ row_tok,
    const int* __restrict__ ttab,
    _Float16* __restrict__ Out, int Ncols)
{
    constexpr int NT = KTOT / 64;
    int ent = ttab[blockIdx.y];
    if (ent < 0) return;
    int e = ent >> 16;
    int m0 = (ent & 0xffff) << 8;
    int Ne = cnt[e];
    int base = offs[e];
    int n0 = blockIdx.x * 256;

    __shared__ __align__(16) _Float16 As[2][256][64];
    __shared__ __align__(16) _Float16 Bs[2][256][64];

    int tid = threadIdx.x;
    int w = tid >> 6;
    int lane = tid & 63;
    int wr = w >> 2, wc = w & 3;
    int fr = lane & 15, fq = lane >> 4;

    // ---- staging sources (pre-swizzled global chunk; LDS dest stays linear) ----
    int trow = tid >> 3;                    // 0..63: row-in-64-group
    int lc = (tid & 7) ^ (trow & 7);        // logical 16B chunk for this lane
    int ar0 = m0 + 0 * 64 + trow; if (ar0 >= Ne) ar0 = Ne - 1;
    int ar1 = m0 + 1 * 64 + trow; if (ar1 >= Ne) ar1 = Ne - 1;
    int ar2 = m0 + 2 * 64 + trow; if (ar2 >= Ne) ar2 = Ne - 1;
    int ar3 = m0 + 3 * 64 + trow; if (ar3 >= Ne) ar3 = Ne - 1;
    int id0 = GATHER ? row_tok[base + ar0] : (base + ar0);
    int id1 = GATHER ? row_tok[base + ar1] : (base + ar1);
    int id2 = GATHER ? row_tok[base + ar2] : (base + ar2);
    int id3 = GATHER ? row_tok[base + ar3] : (base + ar3);
    const _Float16* aSrc0 = Aglob + (size_t)id0 * KTOT + lc * 8;
    const _Float16* aSrc1 = Aglob + (size_t)id1 * KTOT + lc * 8;
    const _Float16* aSrc2 = Aglob + (size_t)id2 * KTOT + lc * 8;
    const _Float16* aSrc3 = Aglob + (size_t)id3 * KTOT + lc * 8;
    const size_t bexp = (size_t)e * Ncols * KTOT;
    const _Float16* bSrc0 = Bglob + bexp + (size_t)(n0 + 0 * 64 + trow) * KTOT + lc * 8;
    const _Float16* bSrc1 = Bglob + bexp + (size_t)(n0 + 1 * 64 + trow) * KTOT + lc * 8;
    const _Float16* bSrc2 = Bglob + bexp + (size_t)(n0 + 2 * 64 + trow) * KTOT + lc * 8;
    const _Float16* bSrc3 = Bglob + bexp + (size_t)(n0 + 3 * 64 + trow) * KTOT + lc * 8;

    _Float16* AsB = &As[0][0][0];
    _Float16* BsB = &Bs[0][0][0];
    _Float16* ldsA = AsB + w * 512;     // + q*4096 + slot*16384
    _Float16* ldsB = BsB + w * 512;

    f32x4 acc[8][4] = {};

    // prologue: stage tile 0 into slot 0 (8 issues)
    glds16(aSrc0, ldsA + 0 * 4096);
    glds16(aSrc1, ldsA + 1 * 4096);
    glds16(aSrc2, ldsA + 2 * 4096);
    glds16(aSrc3, ldsA + 3 * 4096);
    glds16(bSrc0, ldsB + 0 * 4096);
    glds16(bSrc1, ldsB + 1 * 4096);
    glds16(bSrc2, ldsB + 2 * 4096);
    glds16(bSrc3, ldsB + 3 * 4096);

    for (int j = 0; j < NT; ++j) {
        int slot = j & 1;
        const _Float16* Ab = AsB + slot * 16384;
        const _Float16* Bb = BsB + slot * 16384;
        _Float16* An = ldsA + (slot ^ 1) * 16384;
        _Float16* Bn = ldsB + (slot ^ 1) * 16384;
        int koff = (j + 1) * 64;
        bool more = (j + 1 < NT);
        if (more) {
            glds16(aSrc0 + koff, An + 0 * 4096);
            glds16(aSrc1 + koff, An + 1 * 4096);
            glds16(aSrc2 + koff, An + 2 * 4096);
            glds16(aSrc3 + koff, An + 3 * 4096);
            asm volatile("s_waitcnt vmcnt(4)" ::: "memory");
        } else {
            asm volatile("s_waitcnt vmcnt(0)" ::: "memory");
        }
        __builtin_amdgcn_s_barrier();

        f16x8 b_[4][2];
        // ---- phase 0: A-half0 x B-all ----
        {
            f16x8 a_[4][2];
#pragma unroll
            for (int i = 0; i < 4; i++)
#pragma unroll
                for (int k = 0; k < 2; k++)
                    a_[i][k] = lds_read(Ab, wr * 128 + i * 16 + fr, k * 4 + fq);
#pragma unroll
            for (int jj = 0; jj < 4; jj++)
#pragma unroll
                for (int k = 0; k < 2; k++)
                    b_[jj][k] = lds_read(Bb, wc * 64 + jj * 16 + fr, k * 4 + fq);
            if (more) {
                glds16(bSrc0 + koff, Bn + 0 * 4096);
                glds16(bSrc1 + koff, Bn + 1 * 4096);
            }
            __builtin_amdgcn_s_barrier();
            asm volatile("s_waitcnt lgkmcnt(0)" ::: "memory");
            __builtin_amdgcn_s_setprio(1);
#pragma unroll
            for (int i = 0; i < 4; i++)
#pragma unroll
                for (int jj = 0; jj < 4; jj++)
#pragma unroll
                    for (int k = 0; k < 2; k++)
                        acc[i][jj] = __builtin_amdgcn_mfma_f32_16x16x32_f16(
                            a_[i][k], b_[jj][k], acc[i][jj], 0, 0, 0);
            __builtin_amdgcn_s_setprio(0);
            __builtin_amdgcn_s_barrier();
        }
        // ---- phase 1: A-half1 x B-all (B persisted in regs) ----
        {
            f16x8 a_[4][2];
#pragma unroll
            for (int i = 0; i < 4; i++)
#pragma unroll
                for (int k = 0; k < 2; k++)
                    a_[i][k] = lds_read(Ab, wr * 128 + (4 + i) * 16 + fr, k * 4 + fq);
            if (more) {
                glds16(bSrc2 + koff, Bn + 2 * 4096);
                glds16(bSrc3 + koff, Bn + 3 * 4096);
            }
            __builtin_amdgcn_s_barrier();
            asm volatile("s_waitcnt lgkmcnt(0)" ::: "memory");
            __builtin_amdgcn_s_setprio(1);
#pragma unroll
            for (int i = 0; i < 4; i++)
#pragma unroll
                for (int jj = 0; jj < 4; jj++)
#pragma unroll
                    for (int k = 0; k < 2; k++)
                        acc[4 + i][jj] = __builtin_amdgcn_mfma_f32_16x16x32_f16(
                            a_[i][k], b_[jj][k], acc[4 + i][jj], 0, 0, 0);
            __builtin_amdgcn_s_setprio(0);
            __builtin_amdgcn_s_barrier();
        }
    }

    // ---- epilogue ----
#pragma unroll
    for (int mi = 0; mi < 8; mi++) {
#pragma unroll
        for (int r = 0; r < 4; r++) {
            int row = m0 + wr * 128 + mi * 16 + fq * 4 + r;
            if (row < Ne) {
                _Float16* dst = Out + (size_t)(base + row) * Ncols + n0 + wc * 64 + fr;
#pragma unroll
                for (int ni = 0; ni < 4; ni++) {
                    float v = acc[mi][ni][r];
                    if (GELU) v = gelu_tanh(v);
                    dst[ni * 16] = (_Float16)v;
                }
            }
        }
    }
}

// ---------------- combine: out[t] = w0*y[r0] + w1*y[r1] ----------------
__global__ __launch_bounds__(256) void combine_kernel(const _Float16* __restrict__ y,
                                                      const int* __restrict__ tok_row,
                                                      const float* __restrict__ tk_w,
                                                      float* __restrict__ out) {
    int t = blockIdx.x;
    int c = threadIdx.x;
    int r0 = tok_row[2 * t], r1 = tok_row[2 * t + 1];
    float w0 = tk_w[2 * t], w1 = tk_w[2 * t + 1];
    f16x8 a = reinterpret_cast<const f16x8*>(y + (size_t)r0 * HID)[c];
    f16x8 b = reinterpret_cast<const f16x8*>(y + (size_t)r1 * HID)[c];
    float4 o0, o1;
    o0.x = w0 * (float)a[0] + w1 * (float)b[0];
    o0.y = w0 * (float)a[1] + w1 * (float)b[1];
    o0.z = w0 * (float)a[2] + w1 * (float)b[2];
    o0.w = w0 * (float)a[3] + w1 * (float)b[3];
    o1.x = w0 * (float)a[4] + w1 * (float)b[4];
    o1.y = w0 * (float)a[5] + w1 * (float)b[5];
    o1.z = w0 * (float)a[6] + w1 * (float)b[6];
    o1.w = w0 * (float)a[7] + w1 * (float)b[7];
    float4* dst = reinterpret_cast<float4*>(out + (size_t)t * HID + c * 8);
    dst[0] = o0;
    dst[1] = o1;
}

extern "C" void kernel_launch(void* const* d_in, const int* in_sizes, int n_in,
                              void* d_out, int out_size, void* d_ws, size_t ws_size,
                              hipStream_t stream) {
    const float* x  = (const float*)d_in[0];
    const float* gw = (const float*)d_in[1];
    const float* w1 = (const float*)d_in[2];
    const float* w2 = (const float*)d_in[3];
    float* out = (float*)d_out;
    char* ws = (char*)d_ws;

    int*    cnt       = (int*)(ws + 0);
    int*    cursor    = (int*)(ws + 64);
    int*    offs      = (int*)(ws + 128);
    int*    ttab      = (int*)(ws + 512);            // 72*4 bytes
    int*    part_cnt  = (int*)(ws + 4096);           // 8*2048*4 = 64KB
    double* part_sumP = (double*)(ws + 131072);      // 8*2048*8 = 128KB
    int*    row_tok   = (int*)(ws + 262144);         // 64KB
    float*  row_w     = (float*)(ws + 327680);       // 64KB
    int*    tk_idx    = (int*)(ws + 393216);         // 64KB
    float*  tk_w      = (float*)(ws + 458752);       // 64KB
    int*    tok_row   = (int*)(ws + 524288);         // 64KB
    const size_t OFF = 589824;
    _Float16* xh  = (_Float16*)(ws + OFF);                      // 32MB
    _Float16* w1t = (_Float16*)(ws + OFF + (1ull << 25));       // 32MB
    _Float16* w2t = (_Float16*)(ws + OFF + (2ull << 25));       // 32MB
    _Float16* hh  = (_Float16*)(ws + OFF + (3ull << 25));       // 32MB
    _Float16* y   = (_Float16*)(ws + OFF);   // 64MB, aliases xh+w1t (dead after gemm1)

    dim3 g1(INTERM / 32, HID / 32, NEXP);
    tconv_kernel<<<g1, 256, 0, stream>>>(w1, w1t, HID, INTERM);   // w1t[e][i][h]
    dim3 g2(HID / 32, INTERM / 32, NEXP);
    tconv_kernel<<<g2, 256, 0, stream>>>(w2, w2t, INTERM, HID);   // w2t[e][h][i]

    gate_kernel<<<GATE_NB, 256, 0, stream>>>(x, gw, xh, tk_idx, tk_w, part_cnt, part_sumP);
    finalize_kernel<<<1, 256, 0, stream>>>(part_cnt, part_sumP, cnt, offs, cursor, ttab,
                                           out + (size_t)T_TOKENS * HID);
    scatter_kernel<<<T_TOKENS / 256, 256, 0, stream>>>(tk_idx, tk_w, offs, cursor,
                                                       row_tok, row_w, tok_row);

    dim3 gg1(INTERM / 256, MAX_TT, 1);
    gemm8_kernel<true, true, HID><<<gg1, 512, 0, stream>>>(xh, w1t, cnt, offs, row_tok, ttab, hh, INTERM);
    dim3 gg2(HID / 256, MAX_TT, 1);
    gemm8_kernel<false, false, INTERM><<<gg2, 512, 0, stream>>>(hh, w2t, cnt, offs, row_tok, ttab, y, HID);

    combine_kernel<<<T_TOKENS, 256, 0, stream>>>(y, tok_row, tk_w, out);
}

// Round 7
// 409.471 us; speedup vs baseline: 1.1592x; 1.0607x over previous
//
#include <hip/hip_runtime.h>
#include <hip/hip_fp16.h>
#include <cmath>

#define T_TOKENS 8192
#define HID 2048
#define NEXP 8
#define INTERM 1024
#define GATE_NB 2048
#define MAX_TT 136          // sum ceil(cnt_e/128) <= 128+7, padded
#define GEMM_NB 512         // persistent blocks: 2 per CU

typedef _Float16 f16x8 __attribute__((ext_vector_type(8)));
typedef _Float16 f16x4 __attribute__((ext_vector_type(4)));
typedef float f32x4 __attribute__((ext_vector_type(4)));

static __device__ __forceinline__ float gelu_tanh(float v) {
    return 0.5f * v * (1.0f + tanhf(0.79788456080286535588f * (v + 0.044715f * v * v * v)));
}

static __device__ __forceinline__ void glds16(const void* g, void* l) {
    __builtin_amdgcn_global_load_lds((const __attribute__((address_space(1))) void*)g,
                                     (__attribute__((address_space(3))) void*)l, 16, 0, 0);
}

// swizzled LDS read: tile stored [128][64] fp16 (128B rows), phys chunk = chunk ^ (row&7)
static __device__ __forceinline__ f16x8 lds_read(const _Float16* base, int row, int chunk) {
    int phys = chunk ^ (row & 7);
    return *reinterpret_cast<const f16x8*>(
        reinterpret_cast<const char*>(base) + row * 128 + phys * 16);
}

// ------------- fp32 [Z][R][C] -> fp16 [Z][C][R] transpose-convert -------------
__global__ __launch_bounds__(256) void tconv_kernel(const float* __restrict__ in,
                                                    _Float16* __restrict__ out,
                                                    int R, int C) {
    __shared__ float t[32][33];
    int z = blockIdx.z;
    int r0 = blockIdx.y * 32, c0 = blockIdx.x * 32;
    int tid = threadIdx.x;
    int r = tid >> 3, c4 = (tid & 7) * 4;
    const float4 v = *reinterpret_cast<const float4*>(&in[((size_t)z * R + (r0 + r)) * C + c0 + c4]);
    t[r][c4 + 0] = v.x; t[r][c4 + 1] = v.y; t[r][c4 + 2] = v.z; t[r][c4 + 3] = v.w;
    __syncthreads();
    int oc = tid >> 3;
    int or4 = (tid & 7) * 4;
    f16x4 o;
    o[0] = (_Float16)t[or4 + 0][oc];
    o[1] = (_Float16)t[or4 + 1][oc];
    o[2] = (_Float16)t[or4 + 2][oc];
    o[3] = (_Float16)t[or4 + 3][oc];
    *reinterpret_cast<f16x4*>(&out[((size_t)z * C + (c0 + oc)) * R + r0 + or4]) = o;
}

// -------- gating: one wave per token; also emits xh = fp16(x) on the fly --------
__global__ __launch_bounds__(256) void gate_kernel(const float* __restrict__ x,
                                                   const float* __restrict__ gw,
                                                   _Float16* __restrict__ xh,
                                                   int* __restrict__ tk_idx, float* __restrict__ tk_w,
                                                   int* __restrict__ part_cnt,
                                                   double* __restrict__ part_sumP) {
    __shared__ double sds[4][NEXP];
    __shared__ int sci[4][NEXP];
    int w = threadIdx.x >> 6;
    int lane = threadIdx.x & 63;
    int t = blockIdx.x * 4 + w;

    const float4* xr = (const float4*)(x + (size_t)t * HID);
    _Float16* xo = xh + (size_t)t * HID;
    double acc[NEXP];
#pragma unroll
    for (int e = 0; e < NEXP; e++) acc[e] = 0.0;
#pragma unroll
    for (int i = 0; i < HID / 256; i++) {
        float4 xv = xr[i * 64 + lane];
        f16x4 h;
        h[0] = (_Float16)xv.x; h[1] = (_Float16)xv.y;
        h[2] = (_Float16)xv.z; h[3] = (_Float16)xv.w;
        *reinterpret_cast<f16x4*>(xo + i * 256 + lane * 4) = h;
#pragma unroll
        for (int e = 0; e < NEXP; e++) {
            float4 gv = ((const float4*)(gw + (size_t)e * HID))[i * 64 + lane];
            acc[e] += (double)xv.x * (double)gv.x + (double)xv.y * (double)gv.y
                    + (double)xv.z * (double)gv.z + (double)xv.w * (double)gv.w;
        }
    }
#pragma unroll
    for (int e = 0; e < NEXP; e++) {
#pragma unroll
        for (int off = 32; off > 0; off >>= 1) acc[e] += __shfl_xor(acc[e], off, 64);
    }
    double mx = acc[0];
#pragma unroll
    for (int e = 1; e < NEXP; e++) mx = acc[e] > mx ? acc[e] : mx;
    double ex[NEXP];
    double sum = 0.0;
#pragma unroll
    for (int e = 0; e < NEXP; e++) { ex[e] = exp(acc[e] - mx); sum += ex[e]; }
    int i0 = 0;
#pragma unroll
    for (int e = 1; e < NEXP; e++) if (ex[e] > ex[i0]) i0 = e;
    int i1 = (i0 == 0) ? 1 : 0;
#pragma unroll
    for (int e = 0; e < NEXP; e++) if (e != i0 && ex[e] > ex[i1]) i1 = e;
    double p0 = ex[i0], p1 = ex[i1];
    double t2 = p0 + p1;
    if (lane == 0) {
        tk_idx[2 * t] = i0; tk_idx[2 * t + 1] = i1;
        tk_w[2 * t] = (float)(p0 / t2); tk_w[2 * t + 1] = (float)(p1 / t2);
#pragma unroll
        for (int e = 0; e < NEXP; e++) {
            sds[w][e] = ex[e] / sum;
            sci[w][e] = (e == i0 ? 1 : 0) + (e == i1 ? 1 : 0);
        }
    }
    __syncthreads();
    if (threadIdx.x < NEXP) {
        int e = threadIdx.x;
        part_sumP[e * GATE_NB + blockIdx.x] = sds[0][e] + sds[1][e] + sds[2][e] + sds[3][e];
        part_cnt[e * GATE_NB + blockIdx.x]  = sci[0][e] + sci[1][e] + sci[2][e] + sci[3][e];
    }
}

// ------- reduce partials, offsets scan, aux loss, zero cursor, tile table (BM=128) -------
__global__ __launch_bounds__(256) void finalize_kernel(const int* __restrict__ part_cnt,
                                                       const double* __restrict__ part_sumP,
                                                       int* __restrict__ cnt, int* __restrict__ offs,
                                                       int* __restrict__ cursor,
                                                       int* __restrict__ ttab,
                                                       float* __restrict__ aux_out) {
    __shared__ double swv[4];
    __shared__ int cwv[4];
    __shared__ double sE[NEXP];
    __shared__ int cE[NEXP];
    int w = threadIdx.x >> 6;
    int lane = threadIdx.x & 63;
    for (int e = 0; e < NEXP; e++) {
        double s = 0.0; int c = 0;
        for (int j = threadIdx.x; j < GATE_NB; j += 256) {
            s += part_sumP[e * GATE_NB + j];
            c += part_cnt[e * GATE_NB + j];
        }
#pragma unroll
        for (int off = 32; off > 0; off >>= 1) {
            s += __shfl_xor(s, off, 64);
            c += __shfl_xor(c, off, 64);
        }
        if (lane == 0) { swv[w] = s; cwv[w] = c; }
        __syncthreads();
        if (threadIdx.x == 0) {
            sE[e] = swv[0] + swv[1] + swv[2] + swv[3];
            cE[e] = cwv[0] + cwv[1] + cwv[2] + cwv[3];
        }
        __syncthreads();
    }
    if (threadIdx.x == 0) {
        int off = 0;
        double aux = 0.0;
        int idx = 0;
#pragma unroll
        for (int e = 0; e < NEXP; e++) {
            cnt[e] = cE[e];
            offs[e] = off;
            off += cE[e];
            cursor[e] = 0;
            aux += ((double)cE[e] / (double)T_TOKENS) * (sE[e] / (double)T_TOKENS);
            int mt = (cE[e] + 127) >> 7;
            for (int m = 0; m < mt; m++) ttab[idx++] = (e << 16) | m;
        }
        for (; idx < MAX_TT; idx++) ttab[idx] = -1;
        aux_out[0] = (float)(0.01 * (double)NEXP * aux);
    }
}

// ------- build per-expert row lists + inverse map (wave-aggregated atomics) -------
__global__ void scatter_kernel(const int* __restrict__ tk_idx, const float* __restrict__ tk_w,
                               const int* __restrict__ offs, int* __restrict__ cursor,
                               int* __restrict__ row_tok, float* __restrict__ row_w,
                               int* __restrict__ tok_row) {
    int t = blockIdx.x * blockDim.x + threadIdx.x;
    int lane = threadIdx.x & 63;
    unsigned long long below = (lane == 0) ? 0ull : ((~0ull) >> (64 - lane));
    for (int k = 0; k < 2; k++) {
        int e = tk_idx[2 * t + k];
        float wv = tk_w[2 * t + k];
        int pos = 0;
#pragma unroll
        for (int ee = 0; ee < NEXP; ee++) {
            unsigned long long m = __ballot(e == ee);
            if (e == ee) {
                int rank = (int)__popcll(m & below);
                int leader = (int)__ffsll((unsigned long long)m) - 1;
                int b = 0;
                if (lane == leader) b = atomicAdd(&cursor[ee], (int)__popcll(m));
                b = __shfl(b, leader, 64);
                pos = b + rank;
            }
        }
        int r = offs[e] + pos;
        row_tok[r] = t;
        row_w[r] = wv;
        tok_row[2 * t + k] = r;
    }
}

// ============ 128x128 tile, BK=64, 4 waves, persistent items, 2 blocks/CU ============
// Item = (tile_entry, n_tile). Per K-tile: STAGE next slot (8 glds) -> vmcnt(8)
// -> barrier -> phase0 {4 A-reads + 8 B-reads, 16 MFMA} -> phase1 {4 A-reads,
// 16 MFMA, B persisted in regs} -> barrier. LDS 64KB -> 2 blocks/CU overlap.
template<bool GATHER, bool GELU, int KTOT, int NX>
__global__ __launch_bounds__(256, 2) void gemm8_kernel(
    const _Float16* __restrict__ Aglob,
    const _Float16* __restrict__ Bglob,
    const int* __restrict__ cnt, const int* __restrict__ offs,
    const int* __restrict__ row_tok,
    const int* __restrict__ ttab,
    _Float16* __restrict__ Out, int Ncols)
{
    constexpr int NT = KTOT / 64;
    __shared__ __align__(16) _Float16 As[2][128][64];
    __shared__ __align__(16) _Float16 Bs[2][128][64];

    int tid = threadIdx.x;
    int w = tid >> 6, lane = tid & 63;
    int wr = w >> 1, wc = w & 1;
    int fr = lane & 15, fq = lane >> 4;

    int srow = tid >> 3;                   // 0..31 (row within 32-row staging group)
    int lc = (tid & 7) ^ (srow & 7);       // pre-swizzled 16B chunk

    _Float16* ldsA = &As[0][0][0] + w * 512;   // wave-uniform staging base
    _Float16* ldsB = &Bs[0][0][0] + w * 512;

    for (int it = blockIdx.x; it < MAX_TT * NX; it += gridDim.x) {
        int ent = ttab[it / NX];
        if (ent < 0) continue;
        int e = ent >> 16;
        int m0 = (ent & 0xffff) << 7;
        int Ne = cnt[e];
        int base = offs[e];
        int n0 = (it & (NX - 1)) << 7;

        const _Float16* aS[4];
#pragma unroll
        for (int r = 0; r < 4; r++) {
            int ar = m0 + r * 32 + srow; if (ar >= Ne) ar = Ne - 1;
            int id = GATHER ? row_tok[base + ar] : (base + ar);
            aS[r] = Aglob + (size_t)id * KTOT + lc * 8;
        }
        const size_t bexp = (size_t)e * Ncols * KTOT;
        const _Float16* bS[4];
#pragma unroll
        for (int r = 0; r < 4; r++)
            bS[r] = Bglob + bexp + (size_t)(n0 + r * 32 + srow) * KTOT + lc * 8;

#define STAGE(S, KOFF) do {                                         \
        glds16(aS[0] + (KOFF), ldsA + (S) * 8192 + 0 * 2048);       \
        glds16(aS[1] + (KOFF), ldsA + (S) * 8192 + 1 * 2048);       \
        glds16(aS[2] + (KOFF), ldsA + (S) * 8192 + 2 * 2048);       \
        glds16(aS[3] + (KOFF), ldsA + (S) * 8192 + 3 * 2048);       \
        glds16(bS[0] + (KOFF), ldsB + (S) * 8192 + 0 * 2048);       \
        glds16(bS[1] + (KOFF), ldsB + (S) * 8192 + 1 * 2048);       \
        glds16(bS[2] + (KOFF), ldsB + (S) * 8192 + 2 * 2048);       \
        glds16(bS[3] + (KOFF), ldsB + (S) * 8192 + 3 * 2048);       \
    } while (0)

        f32x4 acc[4][4] = {};
        STAGE(0, 0);

        for (int j = 0; j < NT; ++j) {
            int slot = j & 1;
            const _Float16* Ab = &As[slot][0][0];
            const _Float16* Bb = &Bs[slot][0][0];
            if (j + 1 < NT) {
                STAGE(slot ^ 1, (j + 1) * 64);
                asm volatile("s_waitcnt vmcnt(8)" ::: "memory");
            } else {
                asm volatile("s_waitcnt vmcnt(0)" ::: "memory");
            }
            __builtin_amdgcn_s_barrier();

            f16x8 b_[4][2];
            // ---- phase 0: A rows 0..31 x B all ----
            {
                f16x8 a_[2][2];
#pragma unroll
                for (int i = 0; i < 2; i++)
#pragma unroll
                    for (int k = 0; k < 2; k++)
                        a_[i][k] = lds_read(Ab, wr * 64 + i * 16 + fr, k * 4 + fq);
#pragma unroll
                for (int jj = 0; jj < 4; jj++)
#pragma unroll
                    for (int k = 0; k < 2; k++)
                        b_[jj][k] = lds_read(Bb, wc * 64 + jj * 16 + fr, k * 4 + fq);
                asm volatile("s_waitcnt lgkmcnt(0)" ::: "memory");
                __builtin_amdgcn_s_setprio(1);
#pragma unroll
                for (int i = 0; i < 2; i++)
#pragma unroll
                    for (int jj = 0; jj < 4; jj++)
#pragma unroll
                        for (int k = 0; k < 2; k++)
                            acc[i][jj] = __builtin_amdgcn_mfma_f32_16x16x32_f16(
                                a_[i][k], b_[jj][k], acc[i][jj], 0, 0, 0);
                __builtin_amdgcn_s_setprio(0);
            }
            // ---- phase 1: A rows 32..63 x B (persisted) ----
            {
                f16x8 a_[2][2];
#pragma unroll
                for (int i = 0; i < 2; i++)
#pragma unroll
                    for (int k = 0; k < 2; k++)
                        a_[i][k] = lds_read(Ab, wr * 64 + (2 + i) * 16 + fr, k * 4 + fq);
                asm volatile("s_waitcnt lgkmcnt(0)" ::: "memory");
                __builtin_amdgcn_s_setprio(1);
#pragma unroll
                for (int i = 0; i < 2; i++)
#pragma unroll
                    for (int jj = 0; jj < 4; jj++)
#pragma unroll
                        for (int k = 0; k < 2; k++)
                            acc[2 + i][jj] = __builtin_amdgcn_mfma_f32_16x16x32_f16(
                                a_[i][k], b_[jj][k], acc[2 + i][jj], 0, 0, 0);
                __builtin_amdgcn_s_setprio(0);
            }
            __builtin_amdgcn_s_barrier();
        }
#undef STAGE

        // ---- epilogue ----
#pragma unroll
        for (int mi = 0; mi < 4; mi++) {
#pragma unroll
            for (int r = 0; r < 4; r++) {
                int row = m0 + wr * 64 + mi * 16 + fq * 4 + r;
                if (row < Ne) {
                    _Float16* dst = Out + (size_t)(base + row) * Ncols + n0 + wc * 64 + fr;
#pragma unroll
                    for (int ni = 0; ni < 4; ni++) {
                        float v = acc[mi][ni][r];
                        if (GELU) v = gelu_tanh(v);
                        dst[ni * 16] = (_Float16)v;
                    }
                }
            }
        }
    }
}

// ---------------- combine: out[t] = w0*y[r0] + w1*y[r1] ----------------
__global__ __launch_bounds__(256) void combine_kernel(const _Float16* __restrict__ y,
                                                      const int* __restrict__ tok_row,
                                                      const float* __restrict__ tk_w,
                                                      float* __restrict__ out) {
    int t = blockIdx.x;
    int c = threadIdx.x;
    int r0 = tok_row[2 * t], r1 = tok_row[2 * t + 1];
    float w0 = tk_w[2 * t], w1 = tk_w[2 * t + 1];
    f16x8 a = reinterpret_cast<const f16x8*>(y + (size_t)r0 * HID)[c];
    f16x8 b = reinterpret_cast<const f16x8*>(y + (size_t)r1 * HID)[c];
    float4 o0, o1;
    o0.x = w0 * (float)a[0] + w1 * (float)b[0];
    o0.y = w0 * (float)a[1] + w1 * (float)b[1];
    o0.z = w0 * (float)a[2] + w1 * (float)b[2];
    o0.w = w0 * (float)a[3] + w1 * (float)b[3];
    o1.x = w0 * (float)a[4] + w1 * (float)b[4];
    o1.y = w0 * (float)a[5] + w1 * (float)b[5];
    o1.z = w0 * (float)a[6] + w1 * (float)b[6];
    o1.w = w0 * (float)a[7] + w1 * (float)b[7];
    float4* dst = reinterpret_cast<float4*>(out + (size_t)t * HID + c * 8);
    dst[0] = o0;
    dst[1] = o1;
}

extern "C" void kernel_launch(void* const* d_in, const int* in_sizes, int n_in,
                              void* d_out, int out_size, void* d_ws, size_t ws_size,
                              hipStream_t stream) {
    const float* x  = (const float*)d_in[0];
    const float* gw = (const float*)d_in[1];
    const float* w1 = (const float*)d_in[2];
    const float* w2 = (const float*)d_in[3];
    float* out = (float*)d_out;
    char* ws = (char*)d_ws;

    int*    cnt       = (int*)(ws + 0);
    int*    cursor    = (int*)(ws + 64);
    int*    offs      = (int*)(ws + 128);
    int*    ttab      = (int*)(ws + 512);            // 136*4 bytes
    int*    part_cnt  = (int*)(ws + 4096);           // 8*2048*4 = 64KB
    double* part_sumP = (double*)(ws + 131072);      // 8*2048*8 = 128KB
    int*    row_tok   = (int*)(ws + 262144);         // 64KB
    float*  row_w     = (float*)(ws + 327680);       // 64KB
    int*    tk_idx    = (int*)(ws + 393216);         // 64KB
    float*  tk_w      = (float*)(ws + 458752);       // 64KB
    int*    tok_row   = (int*)(ws + 524288);         // 64KB
    const size_t OFF = 589824;
    _Float16* xh  = (_Float16*)(ws + OFF);                      // 32MB
    _Float16* w1t = (_Float16*)(ws + OFF + (1ull << 25));       // 32MB
    _Float16* w2t = (_Float16*)(ws + OFF + (2ull << 25));       // 32MB
    _Float16* hh  = (_Float16*)(ws + OFF + (3ull << 25));       // 32MB
    _Float16* y   = (_Float16*)(ws + OFF);   // 64MB, aliases xh+w1t (dead after gemm1)

    dim3 g1(INTERM / 32, HID / 32, NEXP);
    tconv_kernel<<<g1, 256, 0, stream>>>(w1, w1t, HID, INTERM);   // w1t[e][i][h]
    dim3 g2(HID / 32, INTERM / 32, NEXP);
    tconv_kernel<<<g2, 256, 0, stream>>>(w2, w2t, INTERM, HID);   // w2t[e][h][i]

    gate_kernel<<<GATE_NB, 256, 0, stream>>>(x, gw, xh, tk_idx, tk_w, part_cnt, part_sumP);
    finalize_kernel<<<1, 256, 0, stream>>>(part_cnt, part_sumP, cnt, offs, cursor, ttab,
                                           out + (size_t)T_TOKENS * HID);
    scatter_kernel<<<T_TOKENS / 256, 256, 0, stream>>>(tk_idx, tk_w, offs, cursor,
                                                       row_tok, row_w, tok_row);

    gemm8_kernel<true, true, HID, INTERM / 128>
        <<<GEMM_NB, 256, 0, stream>>>(xh, w1t, cnt, offs, row_tok, ttab, hh, INTERM);
    gemm8_kernel<false, false, INTERM, HID / 128>
        <<<GEMM_NB, 256, 0, stream>>>(hh, w2t, cnt, offs, row_tok, ttab, y, HID);

    combine_kernel<<<T_TOKENS, 256, 0, stream>>>(y, tok_row, tk_w, out);
}